// Round 6
// baseline (472.545 us; speedup 1.0000x reference)
//
#include <hip/hip_runtime.h>
#include <math.h>

#define VOCAB 50000
#define DW 300
#define DH 50
#define G4 200
#define BATCH 1024
#define TMAX 200
#define OUTC 4
#define NB 4   // batch rows per block

// ---------------------------------------------------------------------------
// Kernel 0: transpose + gate-permute w_ih [200][300] -> w_T [300][200] with
// columns u2 = (u%50)*4 + u/50 (unit-major, gate-minor).
__global__ __launch_bounds__(256) void transpose_wih(
    const float* __restrict__ w_ih, float* __restrict__ w_T)
{
    int i = blockIdx.x * 256 + threadIdx.x;
    if (i < G4 * DW) {
        int u = i / DW, k = i % DW;
        int u2 = (u % DH) * 4 + (u / DH);
        w_T[k * G4 + u2] = w_ih[i];
    }
}

// ---------------------------------------------------------------------------
// Kernel A: emb_proj[v][u2] = sum_k emb[v][k]*w_ih[u][k] + b_ih[u] + b_hh[u]
// (unchanged — isolation)
__global__ __launch_bounds__(256, 2) void proj_kernel(
    const float* __restrict__ emb, const float* __restrict__ w_T,
    const float* __restrict__ b_ih, const float* __restrict__ b_hh,
    float* __restrict__ emb_proj)
{
    __shared__ __align__(16) float e_s[100 * 108];  // rows padded to 108 dwords
    const int tid = threadIdx.x;
    const int v0 = blockIdx.x * 100;
    const int m_idx = tid / 25;   // 0..9 (valid for tid<250)
    const int n_idx = tid % 25;   // 0..24

    float acc[10][8];
#pragma unroll
    for (int m = 0; m < 10; m++)
#pragma unroll
        for (int c = 0; c < 8; c++) acc[m][c] = 0.f;

    const float* wcol = w_T + n_idx * 8;

    for (int kc = 0; kc < DW; kc += 100) {
        __syncthreads();   // protect previous chunk reads
        for (int i = tid; i < 2500; i += 256) {
            int r = i / 25, c = i % 25;
            float4 v = *(const float4*)&emb[(size_t)(v0 + r) * DW + kc + c * 4];
            *(float4*)&e_s[r * 108 + c * 4] = v;
        }
        __syncthreads();

        if (tid < 250) {
            float4 wa[4], wb[4];
#pragma unroll
            for (int j = 0; j < 4; j++) {
                const float* p = wcol + (size_t)(kc + j) * G4;
                wa[j] = *(const float4*)p;
                wb[j] = *(const float4*)(p + 4);
            }
            for (int kk = 0; kk < 25; kk++) {
                float4 na[4], nb[4];
                int kn = kc + ((kk < 24) ? (kk + 1) : kk) * 4;
#pragma unroll
                for (int j = 0; j < 4; j++) {
                    const float* p = wcol + (size_t)(kn + j) * G4;
                    na[j] = *(const float4*)p;
                    nb[j] = *(const float4*)(p + 4);
                }
                float4 e4[10];
#pragma unroll
                for (int m = 0; m < 10; m++)
                    e4[m] = *(const float4*)&e_s[(m_idx * 10 + m) * 108 + kk * 4];
#pragma unroll
                for (int j = 0; j < 4; j++) {
#pragma unroll
                    for (int m = 0; m < 10; m++) {
                        float ev = (j == 0) ? e4[m].x : (j == 1) ? e4[m].y
                                 : (j == 2) ? e4[m].z : e4[m].w;
                        acc[m][0] = fmaf(ev, wa[j].x, acc[m][0]);
                        acc[m][1] = fmaf(ev, wa[j].y, acc[m][1]);
                        acc[m][2] = fmaf(ev, wa[j].z, acc[m][2]);
                        acc[m][3] = fmaf(ev, wa[j].w, acc[m][3]);
                        acc[m][4] = fmaf(ev, wb[j].x, acc[m][4]);
                        acc[m][5] = fmaf(ev, wb[j].y, acc[m][5]);
                        acc[m][6] = fmaf(ev, wb[j].z, acc[m][6]);
                        acc[m][7] = fmaf(ev, wb[j].w, acc[m][7]);
                    }
                }
#pragma unroll
                for (int j = 0; j < 4; j++) { wa[j] = na[j]; wb[j] = nb[j]; }
            }
        }
    }

    if (tid < 250) {
        float bias[8];
#pragma unroll
        for (int c = 0; c < 8; c++) {
            int u2 = n_idx * 8 + c;
            int u  = (u2 & 3) * DH + (u2 >> 2);   // inverse gate permutation
            bias[c] = b_ih[u] + b_hh[u];
        }
#pragma unroll
        for (int m = 0; m < 10; m++) {
            float* dst = &emb_proj[(size_t)(v0 + m_idx * 10 + m) * G4 + n_idx * 8];
            *(float4*)dst = make_float4(acc[m][0] + bias[0], acc[m][1] + bias[1],
                                        acc[m][2] + bias[2], acc[m][3] + bias[3]);
            *(float4*)(dst + 4) = make_float4(acc[m][4] + bias[4], acc[m][5] + bias[5],
                                              acc[m][6] + bias[6], acc[m][7] + bias[7]);
        }
    }
}

// ---------------------------------------------------------------------------
// Kernel P: pack w_hh into u2-ordered rows: wp[u2][52] (50 weights + 2 zero
// pads, 208B stride = 16B aligned). Row u2 belongs to gate u2&3, unit u2>>2.
__global__ __launch_bounds__(256) void prep_whh(
    const float* __restrict__ w_hh, float* __restrict__ wp)
{
    int r = threadIdx.x;
    if (r < G4) {
        int gate = r & 3, unit = r >> 2;
        const float* src = w_hh + (size_t)(gate * DH + unit) * DH;
        float* dst = wp + r * 52;
        for (int k = 0; k < DH; k++) dst[k] = src[k];
        dst[50] = 0.f; dst[51] = 0.f;
    }
}

// ---------------------------------------------------------------------------
// Kernel B: NB=4 batch rows per block, 256 threads, thread owns ONE gate-row
// (u2 = tid: gate = tid&3, unit = tid>>2; quad-DPP combine as the verified
// round-3 kernel). Rationale (rounds 0-5): the compiler caps VGPRs at
// 44-140 and re-streams W from L2/scratch every step -> L2 roofline
// (~36 TB/s = the 1630-2160 cyc/step wall). With 4 rows per block the SAME
// W stream serves 4 batch-steps (4x amortization, robust to spilling), and
// the per-thread W footprint drops to 50 floats (13 float4) which may even
// stay resident. Ragged lengths handled by per-row freeze masks
// (block-uniform -> no divergence). One barrier per step.
template <int CTRL>
__device__ __forceinline__ float qbcast(float x) {
    return __int_as_float(__builtin_amdgcn_update_dpp(
        0, __float_as_int(x), CTRL, 0xF, 0xF, true));
}

__global__ __launch_bounds__(256) void lstm_kernel(
    const int* __restrict__ x, const int* __restrict__ lengs,
    const float* __restrict__ emb_proj, const float* __restrict__ wp,
    const float* __restrict__ w_out, const float* __restrict__ b_out,
    float* __restrict__ out)
{
    __shared__ __align__(16) float hbuf[2][NB][52];
    __shared__ int x_s[NB][TMAX];
    __shared__ float red[NB][OUTC];

    const int tid  = threadIdx.x;
    const int b4   = blockIdx.x * NB;
    const int gate = tid & 3;
    const int unit = tid >> 2;
    const int row  = (tid < G4) ? tid : 0;    // W row / gather column

    // stage x rows; zero both h buffers (incl. pads: stale LDS could be NaN,
    // and NaN*0 = NaN in the padded dot)
    for (int i = tid; i < NB * TMAX; i += 256) {
        int nb = i / TMAX, tt = i % TMAX;
        x_s[nb][tt] = x[(size_t)(b4 + nb) * TMAX + tt];
    }
    for (int i = tid; i < 2 * NB * 52; i += 256) ((float*)hbuf)[i] = 0.f;

    const int len0 = lengs[b4 + 0];
    const int len1 = lengs[b4 + 1];
    const int len2 = lengs[b4 + 2];
    const int len3 = lengs[b4 + 3];
    const int lenmax = max(max(len0, len1), max(len2, len3));

    // W row (50 floats + 2 pads) -> 13 float4s
    const float* wr = wp + (size_t)row * 52;
    const float4 W0  = *(const float4*)(wr + 0);
    const float4 W1  = *(const float4*)(wr + 4);
    const float4 W2  = *(const float4*)(wr + 8);
    const float4 W3  = *(const float4*)(wr + 12);
    const float4 W4  = *(const float4*)(wr + 16);
    const float4 W5  = *(const float4*)(wr + 20);
    const float4 W6  = *(const float4*)(wr + 24);
    const float4 W7  = *(const float4*)(wr + 28);
    const float4 W8  = *(const float4*)(wr + 32);
    const float4 W9  = *(const float4*)(wr + 36);
    const float4 W10 = *(const float4*)(wr + 40);
    const float4 W11 = *(const float4*)(wr + 44);
    const float4 W12 = *(const float4*)(wr + 48);

    __syncthreads();   // x_s, hbuf visible

    const float* ep = emb_proj;
    // prefetch depth 2 per row (named scalars only)
    float p00 = ep[(size_t)x_s[0][0] * G4 + row];
    float p01 = ep[(size_t)x_s[0][1] * G4 + row];
    float p10 = ep[(size_t)x_s[1][0] * G4 + row];
    float p11 = ep[(size_t)x_s[1][1] * G4 + row];
    float p20 = ep[(size_t)x_s[2][0] * G4 + row];
    float p21 = ep[(size_t)x_s[2][1] * G4 + row];
    float p30 = ep[(size_t)x_s[3][0] * G4 + row];
    float p31 = ep[(size_t)x_s[3][1] * G4 + row];
    float c0 = 0.f, c1 = 0.f, c2 = 0.f, c3 = 0.f;
    float hp0 = 0.f, hp1 = 0.f, hp2 = 0.f, hp3 = 0.f;

#define DOT4(A, H, W)                                                         \
        A = fmaf((H).x, (W).x, fmaf((H).y, (W).y,                             \
            fmaf((H).z, (W).z, fmaf((H).w, (W).w, A))));

#define STEP_ROW(R, pR0, pR1, cR, hpR, lenR)                                  \
    {                                                                         \
        float cur = pR0; pR0 = pR1;                                           \
        pR1 = ep[(size_t)x_s[R][nt] * G4 + row];                              \
        const float* hb = &hbuf[t & 1][R][0];                                 \
        float4 h0  = *(const float4*)(hb + 0);                                \
        float4 h1  = *(const float4*)(hb + 4);                                \
        float4 h2  = *(const float4*)(hb + 8);                                \
        float4 h3  = *(const float4*)(hb + 12);                               \
        float4 h4  = *(const float4*)(hb + 16);                               \
        float4 h5  = *(const float4*)(hb + 20);                               \
        float4 h6  = *(const float4*)(hb + 24);                               \
        float4 h7  = *(const float4*)(hb + 28);                               \
        float4 h8  = *(const float4*)(hb + 32);                               \
        float4 h9  = *(const float4*)(hb + 36);                               \
        float4 h10 = *(const float4*)(hb + 40);                               \
        float4 h11 = *(const float4*)(hb + 44);                               \
        float4 h12 = *(const float4*)(hb + 48);                               \
        float a0 = cur, a1 = 0.f, a2 = 0.f, a3 = 0.f;                         \
        DOT4(a0, h0,  W0)  DOT4(a1, h1,  W1)                                  \
        DOT4(a2, h2,  W2)  DOT4(a3, h3,  W3)                                  \
        DOT4(a0, h4,  W4)  DOT4(a1, h5,  W5)                                  \
        DOT4(a2, h6,  W6)  DOT4(a3, h7,  W7)                                  \
        DOT4(a0, h8,  W8)  DOT4(a1, h9,  W9)                                  \
        DOT4(a2, h10, W10) DOT4(a3, h11, W11)                                 \
        DOT4(a0, h12, W12)                                                    \
        float g = (a0 + a1) + (a2 + a3);                                      \
        float y = (gate == 2) ? (-2.f * g) : (-g);                            \
        float rr = 1.f / (1.f + __expf(y));                                   \
        float v  = (gate == 2) ? fmaf(2.f, rr, -1.f) : rr;                    \
        float si = qbcast<0x00>(v);                                           \
        float sf = qbcast<0x55>(v);                                           \
        float tc = qbcast<0xAA>(v);                                           \
        float so = qbcast<0xFF>(v);                                           \
        float cn = fmaf(sf, cR, si * tc);                                     \
        bool live = (t < lenR);                                               \
        cn = live ? cn : cR;                                                  \
        cR = cn;                                                              \
        float th = fmaf(2.f, 1.f / (1.f + __expf(-2.f * cn)), -1.f);          \
        float hn = so * th;                                                   \
        hn = live ? hn : hpR;                                                 \
        hpR = hn;                                                             \
        if ((gate == 0) && (tid < G4)) hbuf[(t + 1) & 1][R][unit] = hn;       \
    }

    for (int t = 0; t < lenmax; t++) {
        int nt = (t + 2 < TMAX) ? (t + 2) : (TMAX - 1);
        STEP_ROW(0, p00, p01, c0, hp0, len0)
        STEP_ROW(1, p10, p11, c1, hp1, len1)
        STEP_ROW(2, p20, p21, c2, hp2, len2)
        STEP_ROW(3, p30, p31, c3, hp3, len3)
        __syncthreads();
    }
#undef STEP_ROW
#undef DOT4

    // epilogue: threads 0-15 (wave 0, program-ordered LDS): thread = nb*4+o
    if (tid < NB * OUTC) {
        int nb = tid >> 2, o = tid & 3;
        const float* hf = &hbuf[lenmax & 1][nb][0];
        float lg = b_out[o];
        const float* wo = w_out + o * DH;
#pragma unroll
        for (int k = 0; k < DH; k++) lg = fmaf(hf[k], wo[k], lg);
        red[nb][o] = lg;
        float m = fmaxf(fmaxf(red[nb][0], red[nb][1]),
                        fmaxf(red[nb][2], red[nb][3]));
        float s = 0.f;
#pragma unroll
        for (int j = 0; j < OUTC; j++) s += __expf(red[nb][j] - m);
        out[(size_t)(b4 + nb) * OUTC + o] = __expf(red[nb][o] - m) / s;
    }
}

// ---------------------------------------------------------------------------
extern "C" void kernel_launch(void* const* d_in, const int* in_sizes, int n_in,
                              void* d_out, int out_size, void* d_ws, size_t ws_size,
                              hipStream_t stream) {
    const int*   x     = (const int*)d_in[0];
    const int*   lengs = (const int*)d_in[1];
    const float* emb   = (const float*)d_in[2];
    const float* w_ih  = (const float*)d_in[3];
    const float* w_hh  = (const float*)d_in[4];
    const float* b_ih  = (const float*)d_in[5];
    const float* b_hh  = (const float*)d_in[6];
    const float* w_out = (const float*)d_in[7];
    const float* b_out = (const float*)d_in[8];
    float* out = (float*)d_out;

    float* emb_proj = (float*)d_ws;                       // 40 MB
    float* w_T      = emb_proj + (size_t)VOCAB * G4;      // +240 KB
    float* wp       = w_T;   // reuse: w_T dead after proj_kernel (stream order)

    hipLaunchKernelGGL(transpose_wih, dim3((G4 * DW + 255) / 256), dim3(256),
                       0, stream, w_ih, w_T);
    hipLaunchKernelGGL(proj_kernel, dim3(VOCAB / 100), dim3(256), 0, stream,
                       emb, w_T, b_ih, b_hh, emb_proj);
    hipLaunchKernelGGL(prep_whh, dim3(1), dim3(256), 0, stream, w_hh, wp);
    hipLaunchKernelGGL(lstm_kernel, dim3(BATCH / NB), dim3(256), 0, stream,
                       x, lengs, emb_proj, wp, w_out, b_out, out);
}

// Round 7
// 455.938 us; speedup vs baseline: 1.0364x; 1.0364x over previous
//
#include <hip/hip_runtime.h>
#include <math.h>

#define VOCAB 50000
#define DW 300
#define DH 50
#define G4 200
#define BATCH 1024
#define TMAX 200
#define OUTC 4
#define NB 4   // batch rows per block

// ---------------------------------------------------------------------------
// Kernel 0: transpose + gate-permute w_ih [200][300] -> w_T [300][200] with
// columns u2 = (u%50)*4 + u/50 (unit-major, gate-minor).
__global__ __launch_bounds__(256) void transpose_wih(
    const float* __restrict__ w_ih, float* __restrict__ w_T)
{
    int i = blockIdx.x * 256 + threadIdx.x;
    if (i < G4 * DW) {
        int u = i / DW, k = i % DW;
        int u2 = (u % DH) * 4 + (u / DH);
        w_T[k * G4 + u2] = w_ih[i];
    }
}

// ---------------------------------------------------------------------------
// Kernel A: emb_proj[v][u2] = sum_k emb[v][k]*w_ih[u][k] + b_ih[u] + b_hh[u]
// (unchanged — isolation)
__global__ __launch_bounds__(256, 2) void proj_kernel(
    const float* __restrict__ emb, const float* __restrict__ w_T,
    const float* __restrict__ b_ih, const float* __restrict__ b_hh,
    float* __restrict__ emb_proj)
{
    __shared__ __align__(16) float e_s[100 * 108];  // rows padded to 108 dwords
    const int tid = threadIdx.x;
    const int v0 = blockIdx.x * 100;
    const int m_idx = tid / 25;   // 0..9 (valid for tid<250)
    const int n_idx = tid % 25;   // 0..24

    float acc[10][8];
#pragma unroll
    for (int m = 0; m < 10; m++)
#pragma unroll
        for (int c = 0; c < 8; c++) acc[m][c] = 0.f;

    const float* wcol = w_T + n_idx * 8;

    for (int kc = 0; kc < DW; kc += 100) {
        __syncthreads();   // protect previous chunk reads
        for (int i = tid; i < 2500; i += 256) {
            int r = i / 25, c = i % 25;
            float4 v = *(const float4*)&emb[(size_t)(v0 + r) * DW + kc + c * 4];
            *(float4*)&e_s[r * 108 + c * 4] = v;
        }
        __syncthreads();

        if (tid < 250) {
            float4 wa[4], wb[4];
#pragma unroll
            for (int j = 0; j < 4; j++) {
                const float* p = wcol + (size_t)(kc + j) * G4;
                wa[j] = *(const float4*)p;
                wb[j] = *(const float4*)(p + 4);
            }
            for (int kk = 0; kk < 25; kk++) {
                float4 na[4], nb[4];
                int kn = kc + ((kk < 24) ? (kk + 1) : kk) * 4;
#pragma unroll
                for (int j = 0; j < 4; j++) {
                    const float* p = wcol + (size_t)(kn + j) * G4;
                    na[j] = *(const float4*)p;
                    nb[j] = *(const float4*)(p + 4);
                }
                float4 e4[10];
#pragma unroll
                for (int m = 0; m < 10; m++)
                    e4[m] = *(const float4*)&e_s[(m_idx * 10 + m) * 108 + kk * 4];
#pragma unroll
                for (int j = 0; j < 4; j++) {
#pragma unroll
                    for (int m = 0; m < 10; m++) {
                        float ev = (j == 0) ? e4[m].x : (j == 1) ? e4[m].y
                                 : (j == 2) ? e4[m].z : e4[m].w;
                        acc[m][0] = fmaf(ev, wa[j].x, acc[m][0]);
                        acc[m][1] = fmaf(ev, wa[j].y, acc[m][1]);
                        acc[m][2] = fmaf(ev, wa[j].z, acc[m][2]);
                        acc[m][3] = fmaf(ev, wa[j].w, acc[m][3]);
                        acc[m][4] = fmaf(ev, wb[j].x, acc[m][4]);
                        acc[m][5] = fmaf(ev, wb[j].y, acc[m][5]);
                        acc[m][6] = fmaf(ev, wb[j].z, acc[m][6]);
                        acc[m][7] = fmaf(ev, wb[j].w, acc[m][7]);
                    }
                }
#pragma unroll
                for (int j = 0; j < 4; j++) { wa[j] = na[j]; wb[j] = nb[j]; }
            }
        }
    }

    if (tid < 250) {
        float bias[8];
#pragma unroll
        for (int c = 0; c < 8; c++) {
            int u2 = n_idx * 8 + c;
            int u  = (u2 & 3) * DH + (u2 >> 2);   // inverse gate permutation
            bias[c] = b_ih[u] + b_hh[u];
        }
#pragma unroll
        for (int m = 0; m < 10; m++) {
            float* dst = &emb_proj[(size_t)(v0 + m_idx * 10 + m) * G4 + n_idx * 8];
            *(float4*)dst = make_float4(acc[m][0] + bias[0], acc[m][1] + bias[1],
                                        acc[m][2] + bias[2], acc[m][3] + bias[3]);
            *(float4*)(dst + 4) = make_float4(acc[m][4] + bias[4], acc[m][5] + bias[5],
                                              acc[m][6] + bias[6], acc[m][7] + bias[7]);
        }
    }
}

// ---------------------------------------------------------------------------
// Kernel P: pack w_hh into u2-ordered rows: wp[u2][52] (50 weights + 2 zero
// pads, 208B stride = 16B aligned). Row u2 belongs to gate u2&3, unit u2>>2.
__global__ __launch_bounds__(256) void prep_whh(
    const float* __restrict__ w_hh, float* __restrict__ wp)
{
    int r = threadIdx.x;
    if (r < G4) {
        int gate = r & 3, unit = r >> 2;
        const float* src = w_hh + (size_t)(gate * DH + unit) * DH;
        float* dst = wp + r * 52;
        for (int k = 0; k < DH; k++) dst[k] = src[k];
        dst[50] = 0.f; dst[51] = 0.f;
    }
}

// ---------------------------------------------------------------------------
// Kernel B: NB=4 rows/block, 256 thr, thread = one gate-row (u2 = tid).
// W lives in LDS (wlds[200][52], 41.6 KB; row stride 52 dwords -> lane-start
// banks cycle all 32 in 8 lanes = ds_read_b128 at the HW-minimum 8 phases,
// zero excess conflict). Each W float4 is read ONCE per step into a named
// register and consumed by 16 FMAs (4 rows x 4 elems) immediately — the
// amortization is structural, immune to the register allocator (rounds 0-6:
// per-thread W always demoted, spilled W reloads per USE so NB-reuse never
// materialized; VGPR caps 140/68/44/140/80/68). h reads are same-address
// broadcasts (free, m136). Quad-DPP gate combine + per-row freeze masks as
// the verified R6 kernel. One barrier/step.
template <int CTRL>
__device__ __forceinline__ float qbcast(float x) {
    return __int_as_float(__builtin_amdgcn_update_dpp(
        0, __float_as_int(x), CTRL, 0xF, 0xF, true));
}

__global__ __launch_bounds__(256) void lstm_kernel(
    const int* __restrict__ x, const int* __restrict__ lengs,
    const float* __restrict__ emb_proj, const float* __restrict__ wp,
    const float* __restrict__ w_out, const float* __restrict__ b_out,
    float* __restrict__ out)
{
    __shared__ __align__(16) float wlds[G4 * 52];     // 41.6 KB
    __shared__ __align__(16) float hbuf[2][NB][52];
    __shared__ int x_s[NB][TMAX];
    __shared__ float red[NB][OUTC];

    const int tid  = threadIdx.x;
    const int b4   = blockIdx.x * NB;
    const int gate = tid & 3;
    const int unit = tid >> 2;
    const int row  = (tid < G4) ? tid : 0;    // W row / gather column

    // stage W (coalesced float4; wp already u2-ordered, pads zeroed)
    for (int i = tid; i < G4 * 52 / 4; i += 256)
        ((float4*)wlds)[i] = ((const float4*)wp)[i];
    // stage x rows
    for (int i = tid; i < NB * TMAX; i += 256) {
        int nb = i / TMAX, tt = i % TMAX;
        x_s[nb][tt] = x[(size_t)(b4 + nb) * TMAX + tt];
    }
    // zero both h buffers (incl. pads)
    for (int i = tid; i < 2 * NB * 52; i += 256) ((float*)hbuf)[i] = 0.f;

    const int len0 = lengs[b4 + 0];
    const int len1 = lengs[b4 + 1];
    const int len2 = lengs[b4 + 2];
    const int len3 = lengs[b4 + 3];
    const int lenmax = max(max(len0, len1), max(len2, len3));

    __syncthreads();   // wlds, x_s, hbuf visible

    const float* ep = emb_proj;
    const float* wr = wlds + row * 52;

    // gather prefetch depth 2 per row (named scalars)
    float p00 = ep[(size_t)x_s[0][0] * G4 + row];
    float p01 = ep[(size_t)x_s[0][1] * G4 + row];
    float p10 = ep[(size_t)x_s[1][0] * G4 + row];
    float p11 = ep[(size_t)x_s[1][1] * G4 + row];
    float p20 = ep[(size_t)x_s[2][0] * G4 + row];
    float p21 = ep[(size_t)x_s[2][1] * G4 + row];
    float p30 = ep[(size_t)x_s[3][0] * G4 + row];
    float p31 = ep[(size_t)x_s[3][1] * G4 + row];
    float c0 = 0.f, c1 = 0.f, c2 = 0.f, c3 = 0.f;
    float hp0 = 0.f, hp1 = 0.f, hp2 = 0.f, hp3 = 0.f;

    for (int t = 0; t < lenmax; t++) {
        int nt = (t + 2 < TMAX) ? (t + 2) : (TMAX - 1);
        float cur0 = p00; p00 = p01; p01 = ep[(size_t)x_s[0][nt] * G4 + row];
        float cur1 = p10; p10 = p11; p11 = ep[(size_t)x_s[1][nt] * G4 + row];
        float cur2 = p20; p20 = p21; p21 = ep[(size_t)x_s[2][nt] * G4 + row];
        float cur3 = p30; p30 = p31; p31 = ep[(size_t)x_s[3][nt] * G4 + row];

        const float* hb0 = &hbuf[t & 1][0][0];
        const float* hb1 = &hbuf[t & 1][1][0];
        const float* hb2 = &hbuf[t & 1][2][0];
        const float* hb3 = &hbuf[t & 1][3][0];

        float a0 = cur0, a1 = cur1, a2 = cur2, a3 = cur3;
#pragma unroll
        for (int k4 = 0; k4 < 13; k4++) {
            float4 w4 = *(const float4*)(wr + 4 * k4);    // per-lane row read
            float4 q0 = *(const float4*)(hb0 + 4 * k4);   // broadcast reads
            float4 q1 = *(const float4*)(hb1 + 4 * k4);
            float4 q2 = *(const float4*)(hb2 + 4 * k4);
            float4 q3 = *(const float4*)(hb3 + 4 * k4);
            a0 = fmaf(q0.x, w4.x, fmaf(q0.y, w4.y,
                 fmaf(q0.z, w4.z, fmaf(q0.w, w4.w, a0))));
            a1 = fmaf(q1.x, w4.x, fmaf(q1.y, w4.y,
                 fmaf(q1.z, w4.z, fmaf(q1.w, w4.w, a1))));
            a2 = fmaf(q2.x, w4.x, fmaf(q2.y, w4.y,
                 fmaf(q2.z, w4.z, fmaf(q2.w, w4.w, a2))));
            a3 = fmaf(q3.x, w4.x, fmaf(q3.y, w4.y,
                 fmaf(q3.z, w4.z, fmaf(q3.w, w4.w, a3))));
        }

#define ACT(aR, cR, hpR, lenR, R)                                             \
        {                                                                     \
            float y  = (gate == 2) ? (-2.f * (aR)) : (-(aR));                 \
            float rr = 1.f / (1.f + __expf(y));                               \
            float v  = (gate == 2) ? fmaf(2.f, rr, -1.f) : rr;                \
            float si = qbcast<0x00>(v);                                       \
            float sf = qbcast<0x55>(v);                                       \
            float tc = qbcast<0xAA>(v);                                       \
            float so = qbcast<0xFF>(v);                                       \
            float cn = fmaf(sf, cR, si * tc);                                 \
            bool live = (t < lenR);                                           \
            cn = live ? cn : cR;                                              \
            cR = cn;                                                          \
            float th = fmaf(2.f, 1.f / (1.f + __expf(-2.f * cn)), -1.f);      \
            float hn = so * th;                                               \
            hn = live ? hn : hpR;                                             \
            hpR = hn;                                                         \
            if ((gate == 0) && (tid < G4)) hbuf[(t + 1) & 1][R][unit] = hn;   \
        }
        ACT(a0, c0, hp0, len0, 0)
        ACT(a1, c1, hp1, len1, 1)
        ACT(a2, c2, hp2, len2, 2)
        ACT(a3, c3, hp3, len3, 3)
#undef ACT
        __syncthreads();
    }

    // epilogue: threads 0-15 (wave 0, program-ordered LDS): thread = nb*4+o
    if (tid < NB * OUTC) {
        int nb = tid >> 2, o = tid & 3;
        const float* hf = &hbuf[lenmax & 1][nb][0];
        float lg = b_out[o];
        const float* wo = w_out + o * DH;
#pragma unroll
        for (int k = 0; k < DH; k++) lg = fmaf(hf[k], wo[k], lg);
        red[nb][o] = lg;
        float m = fmaxf(fmaxf(red[nb][0], red[nb][1]),
                        fmaxf(red[nb][2], red[nb][3]));
        float s = 0.f;
#pragma unroll
        for (int j = 0; j < OUTC; j++) s += __expf(red[nb][j] - m);
        out[(size_t)(b4 + nb) * OUTC + o] = __expf(red[nb][o] - m) / s;
    }
}

// ---------------------------------------------------------------------------
extern "C" void kernel_launch(void* const* d_in, const int* in_sizes, int n_in,
                              void* d_out, int out_size, void* d_ws, size_t ws_size,
                              hipStream_t stream) {
    const int*   x     = (const int*)d_in[0];
    const int*   lengs = (const int*)d_in[1];
    const float* emb   = (const float*)d_in[2];
    const float* w_ih  = (const float*)d_in[3];
    const float* w_hh  = (const float*)d_in[4];
    const float* b_ih  = (const float*)d_in[5];
    const float* b_hh  = (const float*)d_in[6];
    const float* w_out = (const float*)d_in[7];
    const float* b_out = (const float*)d_in[8];
    float* out = (float*)d_out;

    float* emb_proj = (float*)d_ws;                       // 40 MB
    float* w_T      = emb_proj + (size_t)VOCAB * G4;      // +240 KB
    float* wp       = w_T;   // reuse: w_T dead after proj_kernel (stream order)

    hipLaunchKernelGGL(transpose_wih, dim3((G4 * DW + 255) / 256), dim3(256),
                       0, stream, w_ih, w_T);
    hipLaunchKernelGGL(proj_kernel, dim3(VOCAB / 100), dim3(256), 0, stream,
                       emb, w_T, b_ih, b_hh, emb_proj);
    hipLaunchKernelGGL(prep_whh, dim3(1), dim3(256), 0, stream, w_hh, wp);
    hipLaunchKernelGGL(lstm_kernel, dim3(BATCH / NB), dim3(256), 0, stream,
                       x, lengs, emb_proj, wp, w_out, b_out, out);
}

// Round 8
// 406.133 us; speedup vs baseline: 1.1635x; 1.1226x over previous
//
#include <hip/hip_runtime.h>
#include <math.h>

#define VOCAB 50000
#define DW 300
#define DH 50
#define G4 200
#define BATCH 1024
#define TMAX 200
#define OUTC 4
#define NB 2   // batch rows per block

// ---------------------------------------------------------------------------
// Kernel 0: transpose + gate-permute w_ih [200][300] -> w_T [300][200] with
// columns u2 = (u%50)*4 + u/50 (unit-major, gate-minor).
__global__ __launch_bounds__(256) void transpose_wih(
    const float* __restrict__ w_ih, float* __restrict__ w_T)
{
    int i = blockIdx.x * 256 + threadIdx.x;
    if (i < G4 * DW) {
        int u = i / DW, k = i % DW;
        int u2 = (u % DH) * 4 + (u / DH);
        w_T[k * G4 + u2] = w_ih[i];
    }
}

// ---------------------------------------------------------------------------
// Kernel A: emb_proj[v][u2] = sum_k emb[v][k]*w_ih[u][k] + b_ih[u] + b_hh[u]
// (unchanged — isolation)
__global__ __launch_bounds__(256, 2) void proj_kernel(
    const float* __restrict__ emb, const float* __restrict__ w_T,
    const float* __restrict__ b_ih, const float* __restrict__ b_hh,
    float* __restrict__ emb_proj)
{
    __shared__ __align__(16) float e_s[100 * 108];  // rows padded to 108 dwords
    const int tid = threadIdx.x;
    const int v0 = blockIdx.x * 100;
    const int m_idx = tid / 25;   // 0..9 (valid for tid<250)
    const int n_idx = tid % 25;   // 0..24

    float acc[10][8];
#pragma unroll
    for (int m = 0; m < 10; m++)
#pragma unroll
        for (int c = 0; c < 8; c++) acc[m][c] = 0.f;

    const float* wcol = w_T + n_idx * 8;

    for (int kc = 0; kc < DW; kc += 100) {
        __syncthreads();   // protect previous chunk reads
        for (int i = tid; i < 2500; i += 256) {
            int r = i / 25, c = i % 25;
            float4 v = *(const float4*)&emb[(size_t)(v0 + r) * DW + kc + c * 4];
            *(float4*)&e_s[r * 108 + c * 4] = v;
        }
        __syncthreads();

        if (tid < 250) {
            float4 wa[4], wb[4];
#pragma unroll
            for (int j = 0; j < 4; j++) {
                const float* p = wcol + (size_t)(kc + j) * G4;
                wa[j] = *(const float4*)p;
                wb[j] = *(const float4*)(p + 4);
            }
            for (int kk = 0; kk < 25; kk++) {
                float4 na[4], nb[4];
                int kn = kc + ((kk < 24) ? (kk + 1) : kk) * 4;
#pragma unroll
                for (int j = 0; j < 4; j++) {
                    const float* p = wcol + (size_t)(kn + j) * G4;
                    na[j] = *(const float4*)p;
                    nb[j] = *(const float4*)(p + 4);
                }
                float4 e4[10];
#pragma unroll
                for (int m = 0; m < 10; m++)
                    e4[m] = *(const float4*)&e_s[(m_idx * 10 + m) * 108 + kk * 4];
#pragma unroll
                for (int j = 0; j < 4; j++) {
#pragma unroll
                    for (int m = 0; m < 10; m++) {
                        float ev = (j == 0) ? e4[m].x : (j == 1) ? e4[m].y
                                 : (j == 2) ? e4[m].z : e4[m].w;
                        acc[m][0] = fmaf(ev, wa[j].x, acc[m][0]);
                        acc[m][1] = fmaf(ev, wa[j].y, acc[m][1]);
                        acc[m][2] = fmaf(ev, wa[j].z, acc[m][2]);
                        acc[m][3] = fmaf(ev, wa[j].w, acc[m][3]);
                        acc[m][4] = fmaf(ev, wb[j].x, acc[m][4]);
                        acc[m][5] = fmaf(ev, wb[j].y, acc[m][5]);
                        acc[m][6] = fmaf(ev, wb[j].z, acc[m][6]);
                        acc[m][7] = fmaf(ev, wb[j].w, acc[m][7]);
                    }
                }
#pragma unroll
                for (int j = 0; j < 4; j++) { wa[j] = na[j]; wb[j] = nb[j]; }
            }
        }
    }

    if (tid < 250) {
        float bias[8];
#pragma unroll
        for (int c = 0; c < 8; c++) {
            int u2 = n_idx * 8 + c;
            int u  = (u2 & 3) * DH + (u2 >> 2);   // inverse gate permutation
            bias[c] = b_ih[u] + b_hh[u];
        }
#pragma unroll
        for (int m = 0; m < 10; m++) {
            float* dst = &emb_proj[(size_t)(v0 + m_idx * 10 + m) * G4 + n_idx * 8];
            *(float4*)dst = make_float4(acc[m][0] + bias[0], acc[m][1] + bias[1],
                                        acc[m][2] + bias[2], acc[m][3] + bias[3]);
            *(float4*)(dst + 4) = make_float4(acc[m][4] + bias[4], acc[m][5] + bias[5],
                                              acc[m][6] + bias[6], acc[m][7] + bias[7]);
        }
    }
}

// ---------------------------------------------------------------------------
// Kernel P: pack w_hh TRANSPOSED + gate-permuted: wpT[k][u2], k = 0..51
// (rows 50,51 zeroed). Column u2 belongs to gate u2&3, unit u2>>2.
// Lane-contiguous in u2 -> conflict-free LDS reads in the lstm kernel.
__global__ __launch_bounds__(256) void prep_whh(
    const float* __restrict__ w_hh, float* __restrict__ wpT)
{
    int r = threadIdx.x;   // u2
    if (r < G4) {
        int gate = r & 3, unit = r >> 2;
        const float* src = w_hh + (size_t)(gate * DH + unit) * DH;
        for (int k = 0; k < 52; k++)
            wpT[k * G4 + r] = (k < DH) ? src[k] : 0.f;
    }
}

// ---------------------------------------------------------------------------
// Kernel B: NB=2 rows/block, 256 thr, grid=512 (2 blocks/CU, 2 waves/SIMD —
// R1's proven latency-hiding regime). Thread = one gate-row (u2 = tid).
// W in LDS TRANSPOSED: wlds[k][u2] -> lane tid reads wlds[k*200+tid]:
// consecutive lanes = consecutive banks, 2 lanes/bank = FREE (fixes R7's
// 531K conflicts from the [200][52] layout's period-8 bank pattern).
// Each W scalar is read per-step and consumed by 2 rows immediately (live
// range ~8 FMAs: nothing to spill, nothing hoistable across the barrier).
// R7's verified freeze-mask / quad-DPP combine retained. One barrier/step.
template <int CTRL>
__device__ __forceinline__ float qbcast(float x) {
    return __int_as_float(__builtin_amdgcn_update_dpp(
        0, __float_as_int(x), CTRL, 0xF, 0xF, true));
}

__global__ __launch_bounds__(256) void lstm_kernel(
    const int* __restrict__ x, const int* __restrict__ lengs,
    const float* __restrict__ emb_proj, const float* __restrict__ wpT,
    const float* __restrict__ w_out, const float* __restrict__ b_out,
    float* __restrict__ out)
{
    __shared__ __align__(16) float wlds[52 * G4];     // [k][u2], 41.6 KB
    __shared__ __align__(16) float hbuf[2][NB][52];
    __shared__ int x_s[NB][TMAX];
    __shared__ float red[NB][OUTC];

    const int tid  = threadIdx.x;
    const int b2   = blockIdx.x * NB;
    const int gate = tid & 3;
    const int unit = tid >> 2;
    const int row  = (tid < G4) ? tid : 0;    // W column / gather column

    // stage W (linear float4 copy; wpT already transposed+permuted+padded)
    for (int i = tid; i < 52 * G4 / 4; i += 256)
        ((float4*)wlds)[i] = ((const float4*)wpT)[i];
    // stage x rows
    for (int i = tid; i < NB * TMAX; i += 256) {
        int nb = i / TMAX, tt = i % TMAX;
        x_s[nb][tt] = x[(size_t)(b2 + nb) * TMAX + tt];
    }
    // zero both h buffers (incl. pads)
    for (int i = tid; i < 2 * NB * 52; i += 256) ((float*)hbuf)[i] = 0.f;

    const int len0 = lengs[b2 + 0];
    const int len1 = lengs[b2 + 1];
    const int lenmax = max(len0, len1);

    __syncthreads();   // wlds, x_s, hbuf visible

    const float* ep = emb_proj;

    float p00 = ep[(size_t)x_s[0][0] * G4 + row];
    float p01 = ep[(size_t)x_s[0][1] * G4 + row];
    float p10 = ep[(size_t)x_s[1][0] * G4 + row];
    float p11 = ep[(size_t)x_s[1][1] * G4 + row];
    float c0 = 0.f, c1 = 0.f;
    float hp0 = 0.f, hp1 = 0.f;

    for (int t = 0; t < lenmax; t++) {
        int nt = (t + 2 < TMAX) ? (t + 2) : (TMAX - 1);
        float cur0 = p00; p00 = p01; p01 = ep[(size_t)x_s[0][nt] * G4 + row];
        float cur1 = p10; p10 = p11; p11 = ep[(size_t)x_s[1][nt] * G4 + row];

        const float* hb0 = &hbuf[t & 1][0][0];
        const float* hb1 = &hbuf[t & 1][1][0];

        // dot: 2 chains per row (alternate k4 parity), W read once / 2 rows
        float a0 = cur0, d0 = 0.f, a1 = cur1, d1 = 0.f;
#pragma unroll
        for (int k4 = 0; k4 < 13; k4++) {
            float4 q0 = *(const float4*)(hb0 + 4 * k4);   // broadcast reads
            float4 q1 = *(const float4*)(hb1 + 4 * k4);
            const float* wk = wlds + (4 * k4) * G4 + row; // conflict-free
            float w0 = wk[0];
            float w1 = wk[G4];
            float w2 = wk[2 * G4];
            float w3 = wk[3 * G4];
            if (k4 & 1) {
                d0 = fmaf(q0.x, w0, fmaf(q0.y, w1,
                     fmaf(q0.z, w2, fmaf(q0.w, w3, d0))));
                d1 = fmaf(q1.x, w0, fmaf(q1.y, w1,
                     fmaf(q1.z, w2, fmaf(q1.w, w3, d1))));
            } else {
                a0 = fmaf(q0.x, w0, fmaf(q0.y, w1,
                     fmaf(q0.z, w2, fmaf(q0.w, w3, a0))));
                a1 = fmaf(q1.x, w0, fmaf(q1.y, w1,
                     fmaf(q1.z, w2, fmaf(q1.w, w3, a1))));
            }
        }
        float g0 = a0 + d0;
        float g1 = a1 + d1;

#define ACT(gR, cR, hpR, lenR, R)                                             \
        {                                                                     \
            float y  = (gate == 2) ? (-2.f * (gR)) : (-(gR));                 \
            float rr = 1.f / (1.f + __expf(y));                               \
            float v  = (gate == 2) ? fmaf(2.f, rr, -1.f) : rr;                \
            float si = qbcast<0x00>(v);                                       \
            float sf = qbcast<0x55>(v);                                       \
            float tc = qbcast<0xAA>(v);                                       \
            float so = qbcast<0xFF>(v);                                       \
            float cn = fmaf(sf, cR, si * tc);                                 \
            bool live = (t < lenR);                                           \
            cn = live ? cn : cR;                                              \
            cR = cn;                                                          \
            float th = fmaf(2.f, 1.f / (1.f + __expf(-2.f * cn)), -1.f);      \
            float hn = so * th;                                               \
            hn = live ? hn : hpR;                                             \
            hpR = hn;                                                         \
            if ((gate == 0) && (tid < G4)) hbuf[(t + 1) & 1][R][unit] = hn;   \
        }
        ACT(g0, c0, hp0, len0, 0)
        ACT(g1, c1, hp1, len1, 1)
#undef ACT
        __syncthreads();
    }

    // epilogue: threads 0-7 (wave 0, program-ordered LDS): thread = nb*4+o
    if (tid < NB * OUTC) {
        int nb = tid >> 2, o = tid & 3;
        const float* hf = &hbuf[lenmax & 1][nb][0];
        float lg = b_out[o];
        const float* wo = w_out + o * DH;
#pragma unroll
        for (int k = 0; k < DH; k++) lg = fmaf(hf[k], wo[k], lg);
        red[nb][o] = lg;
        float m = fmaxf(fmaxf(red[nb][0], red[nb][1]),
                        fmaxf(red[nb][2], red[nb][3]));
        float s = 0.f;
#pragma unroll
        for (int j = 0; j < OUTC; j++) s += __expf(red[nb][j] - m);
        out[(size_t)(b2 + nb) * OUTC + o] = __expf(red[nb][o] - m) / s;
    }
}

// ---------------------------------------------------------------------------
extern "C" void kernel_launch(void* const* d_in, const int* in_sizes, int n_in,
                              void* d_out, int out_size, void* d_ws, size_t ws_size,
                              hipStream_t stream) {
    const int*   x     = (const int*)d_in[0];
    const int*   lengs = (const int*)d_in[1];
    const float* emb   = (const float*)d_in[2];
    const float* w_ih  = (const float*)d_in[3];
    const float* w_hh  = (const float*)d_in[4];
    const float* b_ih  = (const float*)d_in[5];
    const float* b_hh  = (const float*)d_in[6];
    const float* w_out = (const float*)d_in[7];
    const float* b_out = (const float*)d_in[8];
    float* out = (float*)d_out;

    float* emb_proj = (float*)d_ws;                       // 40 MB
    float* w_T      = emb_proj + (size_t)VOCAB * G4;      // +240 KB
    float* wpT      = w_T;   // reuse: w_T dead after proj_kernel (stream order)

    hipLaunchKernelGGL(transpose_wih, dim3((G4 * DW + 255) / 256), dim3(256),
                       0, stream, w_ih, w_T);
    hipLaunchKernelGGL(proj_kernel, dim3(VOCAB / 100), dim3(256), 0, stream,
                       emb, w_T, b_ih, b_hh, emb_proj);
    hipLaunchKernelGGL(prep_whh, dim3(1), dim3(256), 0, stream, w_hh, wpT);
    hipLaunchKernelGGL(lstm_kernel, dim3(BATCH / NB), dim3(256), 0, stream,
                       x, lengs, emb_proj, wpT, w_out, b_out, out);
}

// Round 9
// 323.296 us; speedup vs baseline: 1.4616x; 1.2562x over previous
//
#include <hip/hip_runtime.h>
#include <math.h>

#define VOCAB 50000
#define DW 300
#define DH 50
#define G4 200
#define BATCH 1024
#define TMAX 200
#define OUTC 4

// ---------------------------------------------------------------------------
// Kernel 0: transpose + gate-permute w_ih [200][300] -> w_T [300][200] with
// columns u2 = (u%50)*4 + u/50 (unit-major, gate-minor).
__global__ __launch_bounds__(256) void transpose_wih(
    const float* __restrict__ w_ih, float* __restrict__ w_T)
{
    int i = blockIdx.x * 256 + threadIdx.x;
    if (i < G4 * DW) {
        int u = i / DW, k = i % DW;
        int u2 = (u % DH) * 4 + (u / DH);
        w_T[k * G4 + u2] = w_ih[i];
    }
}

// ---------------------------------------------------------------------------
// Kernel A (rewritten): 50-row tile, 5Mx8N per thread (40 accs).
// R1-R8 counters showed VGPR=112 with ~150 live values (acc80+e4_40+w32):
// the old 10Mx8N tile was spill-throttled at 2 blocks/CU, VALUBusy 33%.
// Now: grid 1000 (~4 blocks/CU), launch_bounds(256,4) caps VGPR at 128
// (fits ~100 live), e_s 21.6KB x4 blocks = 86KB -> 4 indep waves/SIMD.
__global__ __launch_bounds__(256, 4) void proj_kernel(
    const float* __restrict__ emb, const float* __restrict__ w_T,
    const float* __restrict__ b_ih, const float* __restrict__ b_hh,
    float* __restrict__ emb_proj)
{
    __shared__ __align__(16) float e_s[50 * 108];  // rows padded to 108 dwords
    const int tid = threadIdx.x;
    const int v0 = blockIdx.x * 50;
    const int m_idx = tid / 25;   // 0..9 (valid for tid<250): 5 rows each
    const int n_idx = tid % 25;   // 0..24: 8 cols each

    float acc[5][8];
#pragma unroll
    for (int m = 0; m < 5; m++)
#pragma unroll
        for (int c = 0; c < 8; c++) acc[m][c] = 0.f;

    const float* wcol = w_T + n_idx * 8;

    for (int kc = 0; kc < DW; kc += 100) {
        __syncthreads();   // protect previous chunk reads
        for (int i = tid; i < 1250; i += 256) {
            int r = i / 25, c = i % 25;
            float4 v = *(const float4*)&emb[(size_t)(v0 + r) * DW + kc + c * 4];
            *(float4*)&e_s[r * 108 + c * 4] = v;
        }
        __syncthreads();

        if (tid < 250) {
            for (int kk = 0; kk < 25; kk++) {
                float4 e4[5];
#pragma unroll
                for (int m = 0; m < 5; m++)
                    e4[m] = *(const float4*)&e_s[(m_idx * 5 + m) * 108 + kk * 4];
                const float* wbase = wcol + (size_t)(kc + kk * 4) * G4;
#pragma unroll
                for (int j = 0; j < 4; j++) {
                    float4 wa = *(const float4*)(wbase + j * G4);
                    float4 wb = *(const float4*)(wbase + j * G4 + 4);
#pragma unroll
                    for (int m = 0; m < 5; m++) {
                        float ev = (j == 0) ? e4[m].x : (j == 1) ? e4[m].y
                                 : (j == 2) ? e4[m].z : e4[m].w;
                        acc[m][0] = fmaf(ev, wa.x, acc[m][0]);
                        acc[m][1] = fmaf(ev, wa.y, acc[m][1]);
                        acc[m][2] = fmaf(ev, wa.z, acc[m][2]);
                        acc[m][3] = fmaf(ev, wa.w, acc[m][3]);
                        acc[m][4] = fmaf(ev, wb.x, acc[m][4]);
                        acc[m][5] = fmaf(ev, wb.y, acc[m][5]);
                        acc[m][6] = fmaf(ev, wb.z, acc[m][6]);
                        acc[m][7] = fmaf(ev, wb.w, acc[m][7]);
                    }
                }
            }
        }
    }

    if (tid < 250) {
        float bias[8];
#pragma unroll
        for (int c = 0; c < 8; c++) {
            int u2 = n_idx * 8 + c;
            int u  = (u2 & 3) * DH + (u2 >> 2);   // inverse gate permutation
            bias[c] = b_ih[u] + b_hh[u];
        }
#pragma unroll
        for (int m = 0; m < 5; m++) {
            float* dst = &emb_proj[(size_t)(v0 + m_idx * 5 + m) * G4 + n_idx * 8];
            *(float4*)dst = make_float4(acc[m][0] + bias[0], acc[m][1] + bias[1],
                                        acc[m][2] + bias[2], acc[m][3] + bias[3]);
            *(float4*)(dst + 4) = make_float4(acc[m][4] + bias[4], acc[m][5] + bias[5],
                                              acc[m][6] + bias[6], acc[m][7] + bias[7]);
        }
    }
}

// ---------------------------------------------------------------------------
// Kernel B: the verified 136.4us R1 kernel, VERBATIM (best of 6 lstm
// structures tried in rounds 0-8; W-residency and LDS-W approaches are
// structurally capped worse — see round journals). 2 waves/block, thread
// owns 2 gate rows of unit tid/2, DPP quad exchange, 1 barrier/step.
__device__ __forceinline__ float dpp_xor1(float x) {
    // quad_perm [1,0,3,2] : lane 0<->1, 2<->3 within each quad
    return __int_as_float(__builtin_amdgcn_update_dpp(
        0, __float_as_int(x), 0xB1, 0xF, 0xF, true));
}

__global__ __launch_bounds__(128, 2) void lstm_kernel(
    const int* __restrict__ x, const int* __restrict__ lengs,
    const float* __restrict__ emb_proj, const float* __restrict__ w_hh,
    const float* __restrict__ w_out, const float* __restrict__ b_out,
    float* __restrict__ out)
{
    __shared__ __align__(16) float hbuf[2][52];
    __shared__ int x_s[TMAX];
    __shared__ float red[OUTC];

    const int tid = threadIdx.x;
    const int b   = blockIdx.x;
    const int u   = tid >> 1;              // unit 0..63 (>=50 are spares)
    const int uu  = (u < DH) ? u : 0;      // clamp for safe preloads
    const int odd = tid & 1;               // 0: gates i,f ; 1: gates c,o
    const int len = lengs[b];

    for (int i = tid; i < TMAX; i += 128) x_s[i] = x[b * TMAX + i];
    if (tid < 52) hbuf[0][tid] = 0.f;

    // w_hh rows for gates gA=2*odd, gB=2*odd+1 of unit uu -> registers.
    float wA[DH], wB[DH];
    {
        const float* rA = w_hh + (size_t)((2 * odd) * DH + uu) * DH;
        const float* rB = w_hh + (size_t)((2 * odd + 1) * DH + uu) * DH;
#pragma unroll
        for (int k = 0; k < 25; k++) {
            float2 a  = *(const float2*)(rA + 2 * k);
            float2 bb = *(const float2*)(rB + 2 * k);
            wA[2 * k] = a.x;  wA[2 * k + 1] = a.y;
            wB[2 * k] = bb.x; wB[2 * k + 1] = bb.y;
        }
    }
    __syncthreads();

    // gather columns: unit-major gate-minor layout => cols {4u+2*odd, +1}
    const int col = (u < DH) ? (tid * 2) : 0;
    const float* ep = emb_proj;
    float2 p0 = *(const float2*)(ep + (size_t)x_s[0] * G4 + col);
    float2 p1 = *(const float2*)(ep + (size_t)x_s[1] * G4 + col);
    float2 p2 = *(const float2*)(ep + (size_t)x_s[2] * G4 + col);
    float c_reg = 0.f;

    for (int t = 0; t < len; t++) {
        float2 cur = p0; p0 = p1; p1 = p2;
        int nt = t + 3; nt = (nt < TMAX) ? nt : TMAX - 1;
        p2 = *(const float2*)(ep + (size_t)x_s[nt] * G4 + col);

        const float* hb = hbuf[t & 1];
        float accA0 = 0.f, accA1 = 0.f, accB0 = 0.f, accB1 = 0.f;
#pragma unroll
        for (int k4 = 0; k4 < 12; k4++) {
            float4 h4 = *(const float4*)(hb + 4 * k4);
            if ((k4 & 1) == 0) {
                accA0 = fmaf(h4.x, wA[4*k4], fmaf(h4.y, wA[4*k4+1],
                        fmaf(h4.z, wA[4*k4+2], fmaf(h4.w, wA[4*k4+3], accA0))));
                accB0 = fmaf(h4.x, wB[4*k4], fmaf(h4.y, wB[4*k4+1],
                        fmaf(h4.z, wB[4*k4+2], fmaf(h4.w, wB[4*k4+3], accB0))));
            } else {
                accA1 = fmaf(h4.x, wA[4*k4], fmaf(h4.y, wA[4*k4+1],
                        fmaf(h4.z, wA[4*k4+2], fmaf(h4.w, wA[4*k4+3], accA1))));
                accB1 = fmaf(h4.x, wB[4*k4], fmaf(h4.y, wB[4*k4+1],
                        fmaf(h4.z, wB[4*k4+2], fmaf(h4.w, wB[4*k4+3], accB1))));
            }
        }
        {   // tail k = 48,49
            float2 h2 = *(const float2*)(hb + 48);
            accA0 = fmaf(h2.x, wA[48], fmaf(h2.y, wA[49], accA0));
            accB1 = fmaf(h2.x, wB[48], fmaf(h2.y, wB[49], accB1));
        }
        float gA = cur.x + accA0 + accA1;
        float gB = cur.y + accB0 + accB1;

        // even: vA=sig(i), vB=sig(f) ; odd: vA=tanh(c), vB=sig(o)
        float yA = odd ? 2.f * gA : gA;
        float sA = 1.f / (1.f + __expf(-yA));
        float vA = odd ? fmaf(2.f, sA, -1.f) : sA;
        float vB = 1.f / (1.f + __expf(-gB));

        float oA = dpp_xor1(vA);
        float oB = dpp_xor1(vB);
        float si = odd ? oA : vA;
        float sf = odd ? oB : vB;
        float tg = odd ? vA : oA;
        float so = odd ? vB : oB;

        float cn = fmaf(sf, c_reg, si * tg);
        c_reg = cn;                       // identical on both pair threads
        float th = fmaf(2.f, 1.f / (1.f + __expf(-2.f * cn)), -1.f);
        float hn = so * th;
        if (!odd && u < DH) hbuf[(t + 1) & 1][u] = hn;
        __syncthreads();
    }

    // logits + softmax (threads 0-3, all in wave 0: LDS ops program-ordered)
    const float* hf = hbuf[len & 1];
    if (tid < OUTC) {
        float lg = b_out[tid];
        const float* wo = w_out + tid * DH;
#pragma unroll
        for (int k = 0; k < DH; k++) lg = fmaf(hf[k], wo[k], lg);
        red[tid] = lg;
    }
    if (tid < OUTC) {
        float m = fmaxf(fmaxf(red[0], red[1]), fmaxf(red[2], red[3]));
        float s = 0.f;
#pragma unroll
        for (int j = 0; j < OUTC; j++) s += __expf(red[j] - m);
        out[b * OUTC + tid] = __expf(red[tid] - m) / s;
    }
}

// ---------------------------------------------------------------------------
extern "C" void kernel_launch(void* const* d_in, const int* in_sizes, int n_in,
                              void* d_out, int out_size, void* d_ws, size_t ws_size,
                              hipStream_t stream) {
    const int*   x     = (const int*)d_in[0];
    const int*   lengs = (const int*)d_in[1];
    const float* emb   = (const float*)d_in[2];
    const float* w_ih  = (const float*)d_in[3];
    const float* w_hh  = (const float*)d_in[4];
    const float* b_ih  = (const float*)d_in[5];
    const float* b_hh  = (const float*)d_in[6];
    const float* w_out = (const float*)d_in[7];
    const float* b_out = (const float*)d_in[8];
    float* out = (float*)d_out;

    float* emb_proj = (float*)d_ws;                       // 40 MB
    float* w_T      = emb_proj + (size_t)VOCAB * G4;      // +240 KB

    hipLaunchKernelGGL(transpose_wih, dim3((G4 * DW + 255) / 256), dim3(256),
                       0, stream, w_ih, w_T);
    hipLaunchKernelGGL(proj_kernel, dim3(VOCAB / 50), dim3(256), 0, stream,
                       emb, w_T, b_ih, b_hh, emb_proj);
    hipLaunchKernelGGL(lstm_kernel, dim3(BATCH), dim3(128), 0, stream,
                       x, lengs, emb_proj, w_hh, w_out, b_out, out);
}